// Round 1
// baseline (407.445 us; speedup 1.0000x reference)
//
#include <hip/hip_runtime.h>

// Output layout (flat f32, reference return order):
//   out0 : (1024,50,3)  @ 0       (153600)   x0.transpose(0,2,1)
//   steps: (1024,3,49)  @ 153600  (150528)   all 0.01
//   eps  : (1024,3)     @ 304128  (3072)     analytic 0
//   var  : (1024,50,3)  @ 307200  (153600)
//   xi   : (1,10,3)     @ 460800  (30)
#define OUT0_OFF  0
#define STEPS_OFF 153600
#define EPS_OFF   304128
#define VAR_OFF   307200
#define XI_OFF    460800

// ---------------- small matvec (xi MLP): y[j] = act(sum_i x[i]*W[i,j] + b[j]) ----
// block = 256 threads = 8 k-groups x 32 j ; grid.x covers ceil(J/32)
template<bool RELU>
__global__ __launch_bounds__(256)
void matvec_kernel(const float* __restrict__ x, const float* __restrict__ W,
                   const float* __restrict__ bias, const float* __restrict__ mask,
                   float* __restrict__ y, int K, int J)
{
    const int jj = threadIdx.x & 31;
    const int kg = threadIdx.x >> 5;          // 0..7
    const int j  = blockIdx.x * 32 + jj;
    float acc = 0.f;
    const int per = (K + 7) >> 3;
    if (j < J) {
        const int i0 = kg * per;
        const int i1 = min(K, i0 + per);
        for (int i = i0; i < i1; ++i)
            acc = fmaf(x[i], W[i * J + j], acc);
    }
    __shared__ float red[8][32];
    red[kg][jj] = acc;
    __syncthreads();
    if (kg == 0 && j < J) {
        float s = bias[j];
        #pragma unroll
        for (int g = 0; g < 8; ++g) s += red[g][jj];
        if (RELU) s = fmaxf(s, 0.f);
        if (mask) s *= mask[j];
        y[j] = s;
    }
}

// ---------------- f32 tiled GEMM: C = act(A(MxK) @ B(KxN) + bias) -------------
// 64x64 tile, BK=16, 256 threads, 4x4 microtile per thread. Bounds-checked.
#define BM 64
#define BN 64
#define BK 16
#define LPAD 68   // padded leading dim (multiple of 4 for float4 LDS reads)

template<bool RELU>
__global__ __launch_bounds__(256)
void gemm_kernel(const float* __restrict__ A, const float* __restrict__ B,
                 const float* __restrict__ bias, float* __restrict__ C,
                 int M, int N, int K)
{
    __shared__ float As[BK][LPAD];   // As[k][m]
    __shared__ float Bs[BK][LPAD];   // Bs[k][n]
    const int tid  = threadIdx.x;
    const int tx   = tid & 15;       // 16 cols of threads
    const int ty   = tid >> 4;       // 16 rows of threads
    const int row0 = blockIdx.y * BM;
    const int col0 = blockIdx.x * BN;

    // A-tile load map: 64 rows x 16 k; thread -> (row = tid>>2, k0 = (tid&3)*4)
    const int ar  = tid >> 2;
    const int ak0 = (tid & 3) * 4;
    // B-tile load map: 16 k x 64 cols; thread -> (k = tid>>6 + 4*i, col = tid&63)
    const int bc  = tid & 63;
    const int bk0 = tid >> 6;

    float acc[4][4] = {};

    const int ktiles = (K + BK - 1) / BK;
    for (int kt = 0; kt < ktiles; ++kt) {
        const int kb = kt * BK;
        #pragma unroll
        for (int i = 0; i < 4; ++i) {
            const int k = kb + ak0 + i;
            const int r = row0 + ar;
            float v = 0.f;
            if (k < K && r < M) v = A[r * K + k];
            As[ak0 + i][ar] = v;
        }
        #pragma unroll
        for (int i = 0; i < 4; ++i) {
            const int kk = bk0 + i * 4;
            const int k  = kb + kk;
            const int c  = col0 + bc;
            float v = 0.f;
            if (k < K && c < N) v = B[k * N + c];
            Bs[kk][bc] = v;
        }
        __syncthreads();
        #pragma unroll
        for (int kk = 0; kk < BK; ++kk) {
            float a[4], b[4];
            #pragma unroll
            for (int i = 0; i < 4; ++i) a[i] = As[kk][ty * 4 + i];
            #pragma unroll
            for (int jx = 0; jx < 4; ++jx) b[jx] = Bs[kk][tx * 4 + jx];
            #pragma unroll
            for (int i = 0; i < 4; ++i)
                #pragma unroll
                for (int jx = 0; jx < 4; ++jx)
                    acc[i][jx] = fmaf(a[i], b[jx], acc[i][jx]);
        }
        __syncthreads();
    }

    #pragma unroll
    for (int i = 0; i < 4; ++i) {
        const int r = row0 + ty * 4 + i;
        if (r >= M) continue;
        #pragma unroll
        for (int jx = 0; jx < 4; ++jx) {
            const int c = col0 + tx * 4 + jx;
            if (c >= N) continue;
            float v = acc[i][jx] + bias[c];
            if (RELU) v = fmaxf(v, 0.f);
            C[r * N + c] = v;
        }
    }
}

// ---------------- basis -> rhs -> trapezoid integrate + fills -----------------
// One block per batch row b. 64 threads.
__global__ __launch_bounds__(64)
void ode_kernel(const float* __restrict__ var, const float* __restrict__ xi,
                float* __restrict__ out0, float* __restrict__ steps,
                float* __restrict__ eps)
{
    const int b = blockIdx.x;
    const int t = threadIdx.x;
    __shared__ float s_xi[30];         // xi[k][d] flat (10x3)
    __shared__ float s_rhs[50][3];
    if (t < 30) s_xi[t] = xi[t];
    __syncthreads();
    if (t < 50) {
        const float v0 = var[b * 150 + t * 3 + 0];
        const float v1 = var[b * 150 + t * 3 + 1];
        const float v2 = var[b * 150 + t * 3 + 2];
        const float bas[10] = {1.f, v0, v1, v2,
                               v0 * v0, v0 * v1, v0 * v2,
                               v1 * v1, v1 * v2, v2 * v2};
        #pragma unroll
        for (int d = 0; d < 3; ++d) {
            float r = 0.f;
            #pragma unroll
            for (int k = 0; k < 10; ++k) r = fmaf(bas[k], s_xi[k * 3 + d], r);
            s_rhs[t][d] = r;
        }
    }
    __syncthreads();
    if (t < 3) {
        // min-norm lstsq solution == trapezoid integration of rhs from iv
        float x = var[b * 150 + t];          // iv = var[b, 0, t]
        out0[b * 150 + t] = x;
        for (int n = 1; n < 50; ++n) {
            x = fmaf(0.005f, s_rhs[n - 1][t] + s_rhs[n][t], x);  // + 0.5*h*(r0+r1)
            out0[b * 150 + n * 3 + t] = x;
        }
        eps[b * 3 + t] = 0.f;                // residual is exactly 0 analytically
    }
    for (int i = t; i < 147; i += 64) steps[b * 147 + i] = 0.01f;
}

extern "C" void kernel_launch(void* const* d_in, const int* in_sizes, int n_in,
                              void* d_out, int out_size, void* d_ws, size_t ws_size,
                              hipStream_t stream)
{
    const float* net_iv   = (const float*)d_in[0];   // (1024,50,3) -> X (1024x150)
    const float* param_in = (const float*)d_in[1];   // (1,64)
    const float* pW1 = (const float*)d_in[2];
    const float* pb1 = (const float*)d_in[3];
    const float* pW2 = (const float*)d_in[4];
    const float* pb2 = (const float*)d_in[5];
    const float* pW3 = (const float*)d_in[6];
    const float* pb3 = (const float*)d_in[7];
    const float* nW1 = (const float*)d_in[8];
    const float* nb1 = (const float*)d_in[9];
    const float* nW2 = (const float*)d_in[10];
    const float* nb2 = (const float*)d_in[11];
    const float* nW3 = (const float*)d_in[12];
    const float* nb3 = (const float*)d_in[13];
    const float* mask= (const float*)d_in[14];       // (1,10,3)

    float* out   = (float*)d_out;
    float* H1    = (float*)d_ws;            // 1024x1024
    float* H2    = H1 + 1024 * 1024;        // 1024x1024
    float* h1p   = H2 + 1024 * 1024;        // 1024
    float* h2p   = h1p + 1024;              // 1024

    float* out0p  = out + OUT0_OFF;
    float* stepsp = out + STEPS_OFF;
    float* epsp   = out + EPS_OFF;
    float* varp   = out + VAR_OFF;
    float* xip    = out + XI_OFF;

    // xi MLP (tiny)
    hipLaunchKernelGGL((matvec_kernel<true>),  dim3(32), dim3(256), 0, stream,
                       param_in, pW1, pb1, nullptr, h1p, 64, 1024);
    hipLaunchKernelGGL((matvec_kernel<true>),  dim3(32), dim3(256), 0, stream,
                       h1p, pW2, pb2, nullptr, h2p, 1024, 1024);
    hipLaunchKernelGGL((matvec_kernel<false>), dim3(1),  dim3(256), 0, stream,
                       h2p, pW3, pb3, mask, xip, 1024, 30);

    // var MLP (the real work)
    hipLaunchKernelGGL((gemm_kernel<true>),  dim3(16, 16), dim3(256), 0, stream,
                       net_iv, nW1, nb1, H1, 1024, 1024, 150);
    hipLaunchKernelGGL((gemm_kernel<true>),  dim3(16, 16), dim3(256), 0, stream,
                       H1, nW2, nb2, H2, 1024, 1024, 1024);
    hipLaunchKernelGGL((gemm_kernel<false>), dim3(3, 16), dim3(256), 0, stream,
                       H2, nW3, nb3, varp, 1024, 150, 1024);

    // basis -> rhs -> trapezoid + steps/eps fills
    hipLaunchKernelGGL(ode_kernel, dim3(1024), dim3(64), 0, stream,
                       varp, xip, out0p, stepsp, epsp);
}

// Round 2
// 102.382 us; speedup vs baseline: 3.9796x; 3.9796x over previous
//
#include <hip/hip_runtime.h>

// Output layout (flat f32, reference return order):
//   out0 : (1024,50,3)  @ 0       (153600)
//   steps: (1024,3,49)  @ 153600  (150528)  all 0.01
//   eps  : (1024,3)     @ 304128  (3072)    analytic 0
//   var  : (1024,50,3)  @ 307200  (153600)
//   xi   : (1,10,3)     @ 460800  (30)
#define OUT0_OFF  0
#define STEPS_OFF 153600
#define EPS_OFF   304128
#define VAR_OFF   307200
#define XI_OFF    460800

// ---------------- mv1: y[j] = relu(sum_i x[i]*W[i,j] + b[j]), K=64 ------------
template<bool RELU>
__global__ __launch_bounds__(256)
void matvec_kernel(const float* __restrict__ x, const float* __restrict__ W,
                   const float* __restrict__ bias, float* __restrict__ y,
                   int K, int J)
{
    const int jj = threadIdx.x & 31;
    const int kg = threadIdx.x >> 5;          // 0..7
    const int j  = blockIdx.x * 32 + jj;
    float acc = 0.f;
    const int per = (K + 7) >> 3;
    const int i0 = kg * per;
    const int i1 = min(K, i0 + per);
    for (int i = i0; i < i1; ++i)
        acc = fmaf(x[i], W[i * J + j], acc);
    __shared__ float red[8][32];
    red[kg][jj] = acc;
    __syncthreads();
    if (kg == 0) {
        float s = bias[j];
        #pragma unroll
        for (int g = 0; g < 8; ++g) s += red[g][jj];
        if (RELU) s = fmaxf(s, 0.f);
        y[j] = s;
    }
}

// ---------------- mv2a: split-K partial matvec (no bias) ----------------------
__global__ __launch_bounds__(256)
void matvec_part(const float* __restrict__ x, const float* __restrict__ W,
                 float* __restrict__ part, int K, int J, int kchunk)
{
    const int jj = threadIdx.x & 31;
    const int kg = threadIdx.x >> 5;          // 0..7
    const int j  = blockIdx.x * 32 + jj;
    const int ks = blockIdx.y;
    const int per = kchunk >> 3;
    const int i0 = ks * kchunk + kg * per;
    float acc = 0.f;
    for (int i = i0; i < i0 + per; ++i)
        acc = fmaf(x[i], W[i * J + j], acc);
    __shared__ float red[8][32];
    red[kg][jj] = acc;
    __syncthreads();
    if (kg == 0) {
        float s = 0.f;
        #pragma unroll
        for (int g = 0; g < 8; ++g) s += red[g][jj];
        part[ks * J + j] = s;
    }
}

// ---------------- mv3: xi[j] = (sum_k relu(h2[k]) * W3[k,j] + b3[j]) * mask ---
// h2 recomputed on the fly from mv2a partials. One block per j (30 blocks).
__global__ __launch_bounds__(256)
void mv3_kernel(const float* __restrict__ part, const float* __restrict__ b2,
                const float* __restrict__ W3, const float* __restrict__ b3,
                const float* __restrict__ mask, float* __restrict__ xi, int KS)
{
    const int j = blockIdx.x;      // 0..29
    const int t = threadIdx.x;
    float acc = 0.f;
    for (int k = t; k < 1024; k += 256) {
        float h = b2[k];
        for (int s = 0; s < KS; ++s) h += part[s * 1024 + k];
        h = fmaxf(h, 0.f);
        acc = fmaf(h, W3[k * 30 + j], acc);
    }
    __shared__ float red[256];
    red[t] = acc;
    __syncthreads();
    for (int off = 128; off > 0; off >>= 1) {
        if (t < off) red[t] += red[t + off];
        __syncthreads();
    }
    if (t == 0) xi[j] = (red[0] + b3[j]) * mask[j];
}

// ---------------- GEMM1: H1 = relu(net_iv(1024x150) @ nW1(150x1024) + b) ------
// BM=32, BN=64, full K in LDS, one barrier. Grid (16,32), 256 thr, micro 2x4.
__global__ __launch_bounds__(256)
void gemm_k150(const float* __restrict__ A, const float* __restrict__ B,
               const float* __restrict__ bias, float* __restrict__ C)
{
    __shared__ __align__(16) float As[32][150];   // 19.2 KB (row-major, = global)
    __shared__ __align__(16) float Bs[150][64];   // 38.4 KB
    const int t = threadIdx.x;
    const int col0 = blockIdx.x * 64;
    const int row0 = blockIdx.y * 32;

    // A tile: 32 consecutive rows x 150 = contiguous 4800 floats -> float4 copy
    {
        const float4* Asrc = (const float4*)(A + row0 * 150);
        float4* Adst = (float4*)&As[0][0];
        for (int i = t; i < 1200; i += 256) Adst[i] = Asrc[i];
    }
    // B tile: 150 rows x 64 cols, float4 per 16-lane group
    {
        const int kr = t >> 4;
        const int c4 = (t & 15) * 4;
        for (int k = kr; k < 150; k += 16)
            *(float4*)&Bs[k][c4] = *(const float4*)(B + k * 1024 + col0 + c4);
    }
    __syncthreads();

    const int tx = t & 15;        // 16 col-groups * 4
    const int ty = t >> 4;        // 16 row-groups * 2
    float acc[2][4] = {};
    for (int kk = 0; kk < 150; kk += 2) {
        float2 a0 = *(const float2*)&As[ty * 2 + 0][kk];
        float2 a1 = *(const float2*)&As[ty * 2 + 1][kk];
        float4 b0 = *(const float4*)&Bs[kk][tx * 4];
        float4 b1 = *(const float4*)&Bs[kk + 1][tx * 4];
        acc[0][0] = fmaf(a0.x, b0.x, acc[0][0]); acc[0][1] = fmaf(a0.x, b0.y, acc[0][1]);
        acc[0][2] = fmaf(a0.x, b0.z, acc[0][2]); acc[0][3] = fmaf(a0.x, b0.w, acc[0][3]);
        acc[1][0] = fmaf(a1.x, b0.x, acc[1][0]); acc[1][1] = fmaf(a1.x, b0.y, acc[1][1]);
        acc[1][2] = fmaf(a1.x, b0.z, acc[1][2]); acc[1][3] = fmaf(a1.x, b0.w, acc[1][3]);
        acc[0][0] = fmaf(a0.y, b1.x, acc[0][0]); acc[0][1] = fmaf(a0.y, b1.y, acc[0][1]);
        acc[0][2] = fmaf(a0.y, b1.z, acc[0][2]); acc[0][3] = fmaf(a0.y, b1.w, acc[0][3]);
        acc[1][0] = fmaf(a1.y, b1.x, acc[1][0]); acc[1][1] = fmaf(a1.y, b1.y, acc[1][1]);
        acc[1][2] = fmaf(a1.y, b1.z, acc[1][2]); acc[1][3] = fmaf(a1.y, b1.w, acc[1][3]);
    }
    #pragma unroll
    for (int i = 0; i < 2; ++i) {
        const int r = row0 + ty * 2 + i;
        #pragma unroll
        for (int j = 0; j < 4; ++j) {
            const int c = col0 + tx * 4 + j;
            C[r * 1024 + c] = fmaxf(acc[i][j] + bias[c], 0.f);
        }
    }
}

// ---------------- generic 64x64x(BK=16) GEMM, double-buffered, split-K --------
// ACT: 0 = raw partial, 1 = bias+relu, 2 = bias only. B4: B rows 16B-aligned.
template<int ACT, bool B4>
__global__ __launch_bounds__(256)
void gemm64(const float* __restrict__ A, const float* __restrict__ B,
            const float* __restrict__ bias, float* __restrict__ C,
            int N, int K, int kchunk, int pstride)
{
    __shared__ __align__(16) float As[2][16][68];
    __shared__ __align__(16) float Bs[2][16][64];
    const int t = threadIdx.x;
    const int col0 = blockIdx.x * 64;
    const int row0 = blockIdx.y * 64;
    const int k0   = blockIdx.z * kchunk;
    const int nk   = kchunk >> 4;

    const int ar = t >> 2, ak = (t & 3) << 2;     // A stage: row, k-quad
    const int bk = t >> 4, bc = (t & 15) << 2;    // B stage: k, col-quad
    const float* Ap0 = A + (row0 + ar) * K + k0 + ak;
    const float* Bp0 = B + (k0 + bk) * N + col0 + bc;

    float4 a4, b4;
    auto loadB = [&](const float* Bp) {
        if (B4) {
            b4 = *(const float4*)Bp;
        } else {
            const int c = col0 + bc;
            b4.x = (c + 0 < N) ? Bp[0] : 0.f;
            b4.y = (c + 1 < N) ? Bp[1] : 0.f;
            b4.z = (c + 2 < N) ? Bp[2] : 0.f;
            b4.w = (c + 3 < N) ? Bp[3] : 0.f;
        }
    };

    a4 = *(const float4*)Ap0;
    loadB(Bp0);
    As[0][ak + 0][ar] = a4.x; As[0][ak + 1][ar] = a4.y;
    As[0][ak + 2][ar] = a4.z; As[0][ak + 3][ar] = a4.w;
    *(float4*)&Bs[0][bk][bc] = b4;
    __syncthreads();

    const int tx = t & 15, ty = t >> 4;
    float acc[4][4] = {};
    for (int kt = 0; kt < nk; ++kt) {
        const int cur = kt & 1, nxt = cur ^ 1;
        if (kt + 1 < nk) {
            a4 = *(const float4*)(Ap0 + (kt + 1) * 16);
            loadB(Bp0 + (size_t)(kt + 1) * 16 * N);
            As[nxt][ak + 0][ar] = a4.x; As[nxt][ak + 1][ar] = a4.y;
            As[nxt][ak + 2][ar] = a4.z; As[nxt][ak + 3][ar] = a4.w;
            *(float4*)&Bs[nxt][bk][bc] = b4;
        }
        #pragma unroll
        for (int kk = 0; kk < 16; ++kk) {
            float4 av = *(const float4*)&As[cur][kk][ty << 2];
            float4 bv = *(const float4*)&Bs[cur][kk][tx << 2];
            float a[4] = {av.x, av.y, av.z, av.w};
            float b[4] = {bv.x, bv.y, bv.z, bv.w};
            #pragma unroll
            for (int i = 0; i < 4; ++i)
                #pragma unroll
                for (int j = 0; j < 4; ++j)
                    acc[i][j] = fmaf(a[i], b[j], acc[i][j]);
        }
        __syncthreads();
    }

    float* Cb = C + (size_t)blockIdx.z * pstride;
    #pragma unroll
    for (int i = 0; i < 4; ++i) {
        const int r = row0 + ty * 4 + i;
        #pragma unroll
        for (int j = 0; j < 4; ++j) {
            const int c = col0 + tx * 4 + j;
            if (c < N) {
                float v = acc[i][j];
                if (ACT) {
                    v += bias[c];
                    if (ACT == 1) v = fmaxf(v, 0.f);
                }
                Cb[r * N + c] = v;
            }
        }
    }
}

// ---------------- reduce for GEMM2 split-K=2: H2 = relu(P0+P1+bias) -----------
__global__ __launch_bounds__(256)
void reduce2_kernel(const float* __restrict__ P, const float* __restrict__ bias,
                    float* __restrict__ out)
{
    const int i4 = blockIdx.x * 256 + threadIdx.x;    // 0..262143
    float4 p0 = ((const float4*)P)[i4];
    float4 p1 = ((const float4*)(P + (1 << 20)))[i4];
    const int c0 = (i4 << 2) & 1023;
    float4 bv = *(const float4*)&bias[c0];
    float4 v;
    v.x = fmaxf(p0.x + p1.x + bv.x, 0.f);
    v.y = fmaxf(p0.y + p1.y + bv.y, 0.f);
    v.z = fmaxf(p0.z + p1.z + bv.z, 0.f);
    v.w = fmaxf(p0.w + p1.w + bv.w, 0.f);
    ((float4*)out)[i4] = v;
}

// ---------------- ode: fuse GEMM3 split-K reduce + basis/rhs/trapezoid --------
__global__ __launch_bounds__(64)
void ode_kernel(const float* __restrict__ P3, int ns, const float* __restrict__ nb3,
                const float* __restrict__ xi, float* __restrict__ varp,
                float* __restrict__ out0, float* __restrict__ steps,
                float* __restrict__ eps)
{
    const int b = blockIdx.x;
    const int t = threadIdx.x;
    __shared__ float s_var[150];
    __shared__ float s_xi[30];
    __shared__ float s_rhs[50][3];
    if (t < 30) s_xi[t] = xi[t];
    for (int i = t; i < 150; i += 64) {
        float v = nb3[i];
        for (int s = 0; s < ns; ++s) v += P3[s * 153600 + b * 150 + i];
        s_var[i] = v;
        varp[b * 150 + i] = v;
    }
    __syncthreads();
    if (t < 50) {
        const float v0 = s_var[t * 3 + 0];
        const float v1 = s_var[t * 3 + 1];
        const float v2 = s_var[t * 3 + 2];
        const float bas[10] = {1.f, v0, v1, v2,
                               v0 * v0, v0 * v1, v0 * v2,
                               v1 * v1, v1 * v2, v2 * v2};
        #pragma unroll
        for (int d = 0; d < 3; ++d) {
            float r = 0.f;
            #pragma unroll
            for (int k = 0; k < 10; ++k) r = fmaf(bas[k], s_xi[k * 3 + d], r);
            s_rhs[t][d] = r;
        }
    }
    __syncthreads();
    if (t < 3) {
        float x = s_var[t];                         // iv = var[b,0,t]
        out0[b * 150 + t] = x;
        for (int n = 1; n < 50; ++n) {
            x = fmaf(0.005f, s_rhs[n - 1][t] + s_rhs[n][t], x);
            out0[b * 150 + n * 3 + t] = x;
        }
        eps[b * 3 + t] = 0.f;
    }
    for (int i = t; i < 147; i += 64) steps[b * 147 + i] = 0.01f;
}

extern "C" void kernel_launch(void* const* d_in, const int* in_sizes, int n_in,
                              void* d_out, int out_size, void* d_ws, size_t ws_size,
                              hipStream_t stream)
{
    const float* net_iv   = (const float*)d_in[0];
    const float* param_in = (const float*)d_in[1];
    const float* pW1 = (const float*)d_in[2];
    const float* pb1 = (const float*)d_in[3];
    const float* pW2 = (const float*)d_in[4];
    const float* pb2 = (const float*)d_in[5];
    const float* pW3 = (const float*)d_in[6];
    const float* pb3 = (const float*)d_in[7];
    const float* nW1 = (const float*)d_in[8];
    const float* nb1 = (const float*)d_in[9];
    const float* nW2 = (const float*)d_in[10];
    const float* nb2 = (const float*)d_in[11];
    const float* nW3 = (const float*)d_in[12];
    const float* nb3 = (const float*)d_in[13];
    const float* mask= (const float*)d_in[14];

    float* out = (float*)d_out;
    float* out0p  = out + OUT0_OFF;
    float* stepsp = out + STEPS_OFF;
    float* epsp   = out + EPS_OFF;
    float* varp   = out + VAR_OFF;
    float* xip    = out + XI_OFF;

    // Workspace layout (adaptive to ws_size):
    //  full (>=12.7MB): [H1 4MB][P 4MB][H2 4MB][pvec 32KB][h1p 4KB]
    //  small          : [H1 4MB][H2 4MB][pvec 32KB][h1p 4KB]
    float* H1 = (float*)d_ws;
    const bool full = ws_size >= (size_t)(3u * 1048576u + 9216u) * 4u;
    float* P    = H1 + 1048576;
    float* H2   = full ? (P + 1048576) : (H1 + 1048576);
    float* pvec = H2 + 1048576;
    float* h1p  = pvec + 8192;
    const int KS3 = full ? 8 : 4;      // GEMM3 split-K partials live in H1(+P)

    // xi MLP
    hipLaunchKernelGGL((matvec_kernel<true>), dim3(32), dim3(256), 0, stream,
                       param_in, pW1, pb1, h1p, 64, 1024);
    hipLaunchKernelGGL(matvec_part, dim3(32, 8), dim3(256), 0, stream,
                       h1p, pW2, pvec, 1024, 1024, 128);
    hipLaunchKernelGGL(mv3_kernel, dim3(30), dim3(256), 0, stream,
                       pvec, pb2, pW3, pb3, mask, xip, 8);

    // var MLP
    hipLaunchKernelGGL(gemm_k150, dim3(16, 32), dim3(256), 0, stream,
                       net_iv, nW1, nb1, H1);
    if (full) {
        hipLaunchKernelGGL((gemm64<0, true>), dim3(16, 16, 2), dim3(256), 0, stream,
                           H1, nW2, nullptr, P, 1024, 1024, 512, 1048576);
        hipLaunchKernelGGL(reduce2_kernel, dim3(1024), dim3(256), 0, stream,
                           P, nb2, H2);
    } else {
        hipLaunchKernelGGL((gemm64<1, true>), dim3(16, 16, 1), dim3(256), 0, stream,
                           H1, nW2, nb2, H2, 1024, 1024, 1024, 0);
    }
    hipLaunchKernelGGL((gemm64<0, false>), dim3(3, 16, KS3), dim3(256), 0, stream,
                       H2, nW3, nullptr, H1, 150, 1024, 1024 / KS3, 153600);

    // fused reduce + ode + fills
    hipLaunchKernelGGL(ode_kernel, dim3(1024), dim3(64), 0, stream,
                       H1, KS3, nb3, xip, varp, out0p, stepsp, epsp);
}

// Round 3
// 99.391 us; speedup vs baseline: 4.0994x; 1.0301x over previous
//
#include <hip/hip_runtime.h>

// Output layout (flat f32, reference return order):
//   out0 : (1024,50,3)  @ 0       (153600)
//   steps: (1024,3,49)  @ 153600  (150528)  all 0.01
//   eps  : (1024,3)     @ 304128  (3072)    analytic 0
//   var  : (1024,50,3)  @ 307200  (153600)
//   xi   : (1,10,3)     @ 460800  (30)
#define OUT0_OFF  0
#define STEPS_OFF 153600
#define EPS_OFF   304128
#define VAR_OFF   307200
#define XI_OFF    460800

__device__ __forceinline__ void fma16(const float4& av, const float4& bv,
                                      float acc[4][4]) {
    const float a_[4] = {av.x, av.y, av.z, av.w};
    const float b_[4] = {bv.x, bv.y, bv.z, bv.w};
    #pragma unroll
    for (int i = 0; i < 4; ++i)
        #pragma unroll
        for (int j = 0; j < 4; ++j)
            acc[i][j] = fmaf(a_[i], b_[j], acc[i][j]);
}

// ---------------- mv1: y[j] = relu(sum_i x[i]*W[i,j] + b[j]) ------------------
template<bool RELU>
__global__ __launch_bounds__(256)
void matvec_kernel(const float* __restrict__ x, const float* __restrict__ W,
                   const float* __restrict__ bias, float* __restrict__ y,
                   int K, int J)
{
    const int jj = threadIdx.x & 31;
    const int kg = threadIdx.x >> 5;
    const int j  = blockIdx.x * 32 + jj;
    float acc = 0.f;
    const int per = (K + 7) >> 3;
    const int i0 = kg * per;
    const int i1 = min(K, i0 + per);
    for (int i = i0; i < i1; ++i)
        acc = fmaf(x[i], W[i * J + j], acc);
    __shared__ float red[8][32];
    red[kg][jj] = acc;
    __syncthreads();
    if (kg == 0) {
        float s = bias[j];
        #pragma unroll
        for (int g = 0; g < 8; ++g) s += red[g][jj];
        if (RELU) s = fmaxf(s, 0.f);
        y[j] = s;
    }
}

// ---------------- mv2a: split-K partial matvec (no bias) ----------------------
__global__ __launch_bounds__(256)
void matvec_part(const float* __restrict__ x, const float* __restrict__ W,
                 float* __restrict__ part, int K, int J, int kchunk)
{
    const int jj = threadIdx.x & 31;
    const int kg = threadIdx.x >> 5;
    const int j  = blockIdx.x * 32 + jj;
    const int ks = blockIdx.y;
    const int per = kchunk >> 3;
    const int i0 = ks * kchunk + kg * per;
    float acc = 0.f;
    for (int i = i0; i < i0 + per; ++i)
        acc = fmaf(x[i], W[i * J + j], acc);
    __shared__ float red[8][32];
    red[kg][jj] = acc;
    __syncthreads();
    if (kg == 0) {
        float s = 0.f;
        #pragma unroll
        for (int g = 0; g < 8; ++g) s += red[g][jj];
        part[ks * J + j] = s;
    }
}

// ---------------- mv3: xi[j] = (sum_k relu(h2[k]) * W3[k,j] + b3[j]) * mask ---
__global__ __launch_bounds__(256)
void mv3_kernel(const float* __restrict__ part, const float* __restrict__ b2,
                const float* __restrict__ W3, const float* __restrict__ b3,
                const float* __restrict__ mask, float* __restrict__ xi, int KS)
{
    const int j = blockIdx.x;
    const int t = threadIdx.x;
    float acc = 0.f;
    for (int k = t; k < 1024; k += 256) {
        float h = b2[k];
        for (int s = 0; s < KS; ++s) h += part[s * 1024 + k];
        h = fmaxf(h, 0.f);
        acc = fmaf(h, W3[k * 30 + j], acc);
    }
    __shared__ float red[256];
    red[t] = acc;
    __syncthreads();
    for (int off = 128; off > 0; off >>= 1) {
        if (t < off) red[t] += red[t + off];
        __syncthreads();
    }
    if (t == 0) xi[j] = (red[0] + b3[j]) * mask[j];
}

// ---------------- GEMM1: H1 = relu(net_iv(1024x150) @ nW1(150x1024) + b) ------
// 32x64 tile, 128 thr, whole K in LDS (A transposed), 2-deep reg prefetch.
__global__ __launch_bounds__(128)
void gemm1_k150(const float* __restrict__ A, const float* __restrict__ B,
                const float* __restrict__ bias, float* __restrict__ C)
{
    __shared__ __align__(16) float As[150][36];   // transposed, 21.6 KB
    __shared__ __align__(16) float Bs[150][64];   // 38.4 KB
    const int t = threadIdx.x;
    const int col0 = blockIdx.x * 64;
    const int row0 = blockIdx.y * 32;

    for (int i = t; i < 4800; i += 128) {
        const int r = i / 150;
        const int k = i - r * 150;
        As[k][r] = A[row0 * 150 + i];
    }
    {
        const int c4 = (t & 15) * 4;
        for (int k = t >> 4; k < 150; k += 8)
            *(float4*)&Bs[k][c4] = *(const float4*)(B + k * 1024 + col0 + c4);
    }
    __syncthreads();

    const int tx4 = (t & 15) * 4;
    const int ty4 = (t >> 4) * 4;     // 0..28
    float acc[4][4] = {};
    float4 aA = *(const float4*)&As[0][ty4], bA = *(const float4*)&Bs[0][tx4];
    float4 aB = *(const float4*)&As[1][ty4], bB = *(const float4*)&Bs[1][tx4];
    #pragma unroll 5
    for (int k = 0; k < 150; k += 2) {
        float4 aN0 = {}, bN0 = {}, aN1 = {}, bN1 = {};
        if (k + 2 < 150) {
            aN0 = *(const float4*)&As[k + 2][ty4];
            bN0 = *(const float4*)&Bs[k + 2][tx4];
        }
        if (k + 3 < 150) {
            aN1 = *(const float4*)&As[k + 3][ty4];
            bN1 = *(const float4*)&Bs[k + 3][tx4];
        }
        fma16(aA, bA, acc);
        fma16(aB, bB, acc);
        aA = aN0; bA = bN0; aB = aN1; bB = bN1;
    }
    #pragma unroll
    for (int i = 0; i < 4; ++i) {
        const int r = row0 + ty4 + i;
        #pragma unroll
        for (int j = 0; j < 4; ++j) {
            const int c = col0 + tx4 + j;
            C[r * 1024 + c] = fmaxf(acc[i][j] + bias[c], 0.f);
        }
    }
}

// ---------------- generic tile GEMM: BMx64, BK=16, dbuf LDS, reg prefetch -----
// NT = 4*BM threads. ACT: 0 raw partial, 1 bias+relu. BG: guarded/scalar B.
template<int BM, int NT, int ACT, bool BG>
__global__ __launch_bounds__(NT)
void gemm_tile(const float* __restrict__ A, const float* __restrict__ B,
               const float* __restrict__ bias, float* __restrict__ C,
               int N, int K, int kchunk, long pstride)
{
    constexpr int BI = 1024 / (NT * 4);   // B float4s per thread (256->1,128->2)
    __shared__ __align__(16) float As[2][16][BM + 4];
    __shared__ __align__(16) float Bs[2][16][64];
    const int t = threadIdx.x;
    const int col0 = blockIdx.x * 64;
    const int row0 = blockIdx.y * BM;
    const int k0   = blockIdx.z * kchunk;
    const int nk   = kchunk >> 4;

    const int ar = t >> 2;                // 0..BM-1
    const int ak = (t & 3) << 2;
    const int bc = (t & 15) << 2;
    const int tx4 = (t & 15) << 2;
    const int ty4 = (t >> 4) << 2;

    const float* Ap = A + (long)(row0 + ar) * K + k0 + ak;

    float4 ga, gb[BI];
    auto loadG = [&](int kt) {
        ga = *(const float4*)(Ap + kt * 16);
        #pragma unroll
        for (int i = 0; i < BI; ++i) {
            const int rr = (t >> 4) + i * (NT >> 4);
            const float* Bp = B + (long)(k0 + kt * 16 + rr) * N + col0 + bc;
            if (BG) {
                float4 b4;
                b4.x = (col0 + bc + 0 < N) ? Bp[0] : 0.f;
                b4.y = (col0 + bc + 1 < N) ? Bp[1] : 0.f;
                b4.z = (col0 + bc + 2 < N) ? Bp[2] : 0.f;
                b4.w = (col0 + bc + 3 < N) ? Bp[3] : 0.f;
                gb[i] = b4;
            } else {
                gb[i] = *(const float4*)Bp;
            }
        }
    };
    auto writeL = [&](int buf) {
        As[buf][ak + 0][ar] = ga.x;
        As[buf][ak + 1][ar] = ga.y;
        As[buf][ak + 2][ar] = ga.z;
        As[buf][ak + 3][ar] = ga.w;
        #pragma unroll
        for (int i = 0; i < BI; ++i) {
            const int rr = (t >> 4) + i * (NT >> 4);
            *(float4*)&Bs[buf][rr][bc] = gb[i];
        }
    };

    loadG(0);
    writeL(0);
    __syncthreads();

    float acc[4][4] = {};
    for (int kt = 0; kt < nk; ++kt) {
        const int cur = kt & 1;
        if (kt + 1 < nk) loadG(kt + 1);          // T14: issue early

        float4 aA = *(const float4*)&As[cur][0][ty4];
        float4 bA = *(const float4*)&Bs[cur][0][tx4];
        float4 aB = *(const float4*)&As[cur][1][ty4];
        float4 bB = *(const float4*)&Bs[cur][1][tx4];
        #pragma unroll
        for (int kk = 0; kk < 16; kk += 2) {
            float4 aN0 = {}, bN0 = {}, aN1 = {}, bN1 = {};
            if (kk + 2 < 16) {
                aN0 = *(const float4*)&As[cur][kk + 2][ty4];
                bN0 = *(const float4*)&Bs[cur][kk + 2][tx4];
            }
            if (kk + 3 < 16) {
                aN1 = *(const float4*)&As[cur][kk + 3][ty4];
                bN1 = *(const float4*)&Bs[cur][kk + 3][tx4];
            }
            fma16(aA, bA, acc);
            fma16(aB, bB, acc);
            aA = aN0; bA = bN0; aB = aN1; bB = bN1;
        }

        if (kt + 1 < nk) writeL(cur ^ 1);        // write late
        __syncthreads();
    }

    float* Cb = C + (long)blockIdx.z * pstride;
    #pragma unroll
    for (int i = 0; i < 4; ++i) {
        const int r = row0 + ty4 + i;
        #pragma unroll
        for (int j = 0; j < 4; ++j) {
            const int c = col0 + tx4 + j;
            if (!BG || c < N) {
                float v = acc[i][j];
                if (ACT) { v += bias[c]; if (ACT == 1) v = fmaxf(v, 0.f); }
                Cb[(long)r * N + c] = v;
            }
        }
    }
}

// ---------------- reduce for GEMM2 split-K=2: out = relu(P0+P1+bias) ----------
// out may alias P1 (element-wise, same index) — no restrict on P1/out.
__global__ __launch_bounds__(256)
void reduce2_kernel(const float* __restrict__ P0, const float* P1,
                    const float* __restrict__ bias, float* out)
{
    const int i4 = blockIdx.x * 256 + threadIdx.x;
    float4 p0 = ((const float4*)P0)[i4];
    float4 p1 = ((const float4*)P1)[i4];
    const int c0 = (i4 << 2) & 1023;
    float4 bv = *(const float4*)&bias[c0];
    float4 v;
    v.x = fmaxf(p0.x + p1.x + bv.x, 0.f);
    v.y = fmaxf(p0.y + p1.y + bv.y, 0.f);
    v.z = fmaxf(p0.z + p1.z + bv.z, 0.f);
    v.w = fmaxf(p0.w + p1.w + bv.w, 0.f);
    ((float4*)out)[i4] = v;
}

// ---------------- ode: fuse GEMM3 split-K reduce + basis/rhs/trapezoid --------
__global__ __launch_bounds__(64)
void ode_kernel(const float* __restrict__ P3, int ns, const float* __restrict__ nb3,
                const float* __restrict__ xi, float* __restrict__ varp,
                float* __restrict__ out0, float* __restrict__ steps,
                float* __restrict__ eps)
{
    const int b = blockIdx.x;
    const int t = threadIdx.x;
    __shared__ float s_var[150];
    __shared__ float s_xi[30];
    __shared__ float s_rhs[50][3];
    if (t < 30) s_xi[t] = xi[t];
    for (int i = t; i < 150; i += 64) {
        float v = nb3[i];
        for (int s = 0; s < ns; ++s) v += P3[s * 153600 + b * 150 + i];
        s_var[i] = v;
        varp[b * 150 + i] = v;
    }
    __syncthreads();
    if (t < 50) {
        const float v0 = s_var[t * 3 + 0];
        const float v1 = s_var[t * 3 + 1];
        const float v2 = s_var[t * 3 + 2];
        const float bas[10] = {1.f, v0, v1, v2,
                               v0 * v0, v0 * v1, v0 * v2,
                               v1 * v1, v1 * v2, v2 * v2};
        #pragma unroll
        for (int d = 0; d < 3; ++d) {
            float r = 0.f;
            #pragma unroll
            for (int k = 0; k < 10; ++k) r = fmaf(bas[k], s_xi[k * 3 + d], r);
            s_rhs[t][d] = r;
        }
    }
    __syncthreads();
    if (t < 3) {
        float x = s_var[t];
        out0[b * 150 + t] = x;
        for (int n = 1; n < 50; ++n) {
            x = fmaf(0.005f, s_rhs[n - 1][t] + s_rhs[n][t], x);
            out0[b * 150 + n * 3 + t] = x;
        }
        eps[b * 3 + t] = 0.f;
    }
    for (int i = t; i < 147; i += 64) steps[b * 147 + i] = 0.01f;
}

extern "C" void kernel_launch(void* const* d_in, const int* in_sizes, int n_in,
                              void* d_out, int out_size, void* d_ws, size_t ws_size,
                              hipStream_t stream)
{
    const float* net_iv   = (const float*)d_in[0];
    const float* param_in = (const float*)d_in[1];
    const float* pW1 = (const float*)d_in[2];
    const float* pb1 = (const float*)d_in[3];
    const float* pW2 = (const float*)d_in[4];
    const float* pb2 = (const float*)d_in[5];
    const float* pW3 = (const float*)d_in[6];
    const float* pb3 = (const float*)d_in[7];
    const float* nW1 = (const float*)d_in[8];
    const float* nb1 = (const float*)d_in[9];
    const float* nW2 = (const float*)d_in[10];
    const float* nb2 = (const float*)d_in[11];
    const float* nW3 = (const float*)d_in[12];
    const float* nb3 = (const float*)d_in[13];
    const float* mask= (const float*)d_in[14];

    float* out = (float*)d_out;
    float* out0p  = out + OUT0_OFF;
    float* stepsp = out + STEPS_OFF;
    float* epsp   = out + EPS_OFF;
    float* varp   = out + VAR_OFF;
    float* xip    = out + XI_OFF;

    // ws layout: [W0 4MB][W1 4MB][W2 4MB][pvec 32KB][h1p 4KB]  (= R2 footprint)
    float* W0 = (float*)d_ws;
    float* W1 = W0 + 1048576;
    float* W2 = W1 + 1048576;
    float* pvec = W2 + 1048576;
    float* h1p  = pvec + 8192;
    const bool full = ws_size >= (size_t)(3u * 1048576u + 9216u) * 4u;

    // xi MLP
    hipLaunchKernelGGL((matvec_kernel<true>), dim3(32), dim3(256), 0, stream,
                       param_in, pW1, pb1, h1p, 64, 1024);
    hipLaunchKernelGGL(matvec_part, dim3(32, 8), dim3(256), 0, stream,
                       h1p, pW2, pvec, 1024, 1024, 128);
    hipLaunchKernelGGL(mv3_kernel, dim3(30), dim3(256), 0, stream,
                       pvec, pb2, pW3, pb3, mask, xip, 8);

    // GEMM1: net_iv @ nW1 -> H1 = W0
    hipLaunchKernelGGL(gemm1_k150, dim3(16, 32), dim3(128), 0, stream,
                       net_iv, nW1, nb1, W0);

    if (full) {
        // GEMM2 split-K=2: partials -> W1, W2 ; reduce in-place -> H2 = W2
        hipLaunchKernelGGL((gemm_tile<64, 256, 0, false>), dim3(16, 16, 2),
                           dim3(256), 0, stream,
                           W0, nW2, nullptr, W1, 1024, 1024, 512, 1048576L);
        hipLaunchKernelGGL(reduce2_kernel, dim3(1024), dim3(256), 0, stream,
                           W1, W2, nb2, W2);
        // GEMM3 split-K=8: partials -> W0 (spills into free W1)
        hipLaunchKernelGGL((gemm_tile<32, 128, 0, true>), dim3(3, 32, 8),
                           dim3(128), 0, stream,
                           W2, nW3, nullptr, W0, 150, 1024, 128, 153600L);
        hipLaunchKernelGGL(ode_kernel, dim3(1024), dim3(64), 0, stream,
                           W0, 8, nb3, xip, varp, out0p, stepsp, epsp);
    } else {
        // fallback: no split-K part若 workspace is small
        hipLaunchKernelGGL((gemm_tile<64, 256, 1, false>), dim3(16, 16, 1),
                           dim3(256), 0, stream,
                           W0, nW2, nb2, W1, 1024, 1024, 1024, 0L);
        hipLaunchKernelGGL((gemm_tile<32, 128, 0, true>), dim3(3, 32, 4),
                           dim3(128), 0, stream,
                           W1, nW3, nullptr, W0, 150, 1024, 256, 153600L);
        hipLaunchKernelGGL(ode_kernel, dim3(1024), dim3(64), 0, stream,
                           W0, 4, nb3, xip, varp, out0p, stepsp, epsp);
    }
}